// Round 10
// baseline (465.614 us; speedup 1.0000x reference)
//
#include <hip/hip_runtime.h>
#include <hip/hip_bf16.h>

typedef unsigned short u16;
typedef unsigned int u32;
typedef __attribute__((ext_vector_type(8))) short s8v;   // 8 x bf16
typedef __attribute__((ext_vector_type(4))) float f4v;   // mfma acc

__device__ __forceinline__ float b2f(u16 u) {
  union { u32 i; float f; } v; v.i = ((u32)u) << 16; return v.f;
}
__device__ __forceinline__ u16 f2b(float f) {
  union { float f; u32 i; } v; v.f = f;
  u32 r = v.i + 0x7FFFu + ((v.i >> 16) & 1u);
  return (u16)(r >> 16);
}
__device__ __forceinline__ float rcpf(float x) { return __builtin_amdgcn_rcpf(x); }
__device__ __forceinline__ float ex2(float x) {
#if __has_builtin(__builtin_amdgcn_exp2f)
  return __builtin_amdgcn_exp2f(x);
#else
  return exp2f(x);
#endif
}
__device__ __forceinline__ float sigf(float x) { return rcpf(1.0f + __expf(-x)); }

#define GS_IFO 1.4426950408889634f
#define GS_G   2.8853900817779268f

__device__ __forceinline__ void gl_lds16(const u16* g, u16* l) {
  __builtin_amdgcn_global_load_lds(
      (const __attribute__((address_space(1))) u32*)g,
      (__attribute__((address_space(3))) u32*)l, 16, 0, 0);
}

// ---------------- weight conversion fp32 -> bf16 ----------------
// scl: 0 none, 1 gate-pattern scale (exp2 domain), 2 uniform log2e. sh: log2(float4s/row).
struct CvtArgs {
  const float* src[9];
  u16* dst[9];
  int n4[9];
  int scl[9];
  int sh[9];
};
__global__ __launch_bounds__(256) void k_cvt(CvtArgs a) {
  int seg = blockIdx.y;
  int i = blockIdx.x * 256 + threadIdx.x;
  if (i >= a.n4[seg]) return;
  float4 v = ((const float4*)a.src[seg])[i];
  if (a.scl[seg]) {
    float s;
    if (a.scl[seg] == 2) {
      s = GS_IFO;
    } else {
      int r = i >> a.sh[seg];
      s = (((r >> 7) & 3) == 2) ? GS_G : GS_IFO;
    }
    v.x *= s; v.y *= s; v.z *= s; v.w *= s;
  }
  ushort4 o;
  o.x = f2b(v.x); o.y = f2b(v.y); o.z = f2b(v.z); o.w = f2b(v.w);
  ((ushort4*)a.dst[seg])[i] = o;
}

// ------- transpose input [B,C,H,W] -> A_h bf16 [(b,w,h)][c]; also channel means -------
__global__ __launch_bounds__(256) void k_tin(const float* __restrict__ in,
                                             u16* __restrict__ A,
                                             float* __restrict__ meansum) {
  int b = blockIdx.z, h = blockIdx.y, c0 = blockIdx.x * 64;
  int t = threadIdx.x, lane = t & 63, q = t >> 6;
  __shared__ u16 lT[64][66];
  const float* src = in + ((b * 256 + c0) * 64 + h) * 64;
#pragma unroll 4
  for (int i = 0; i < 16; ++i) {
    int cl = q * 16 + i;
    float v = src[cl * 4096 + lane];
    lT[cl][lane] = f2b(v);
    float s = v;
#pragma unroll
    for (int off = 32; off; off >>= 1) s += __shfl_xor(s, off);
    if (lane == 0) atomicAdd(&meansum[b * 256 + c0 + cl], s);
  }
  __syncthreads();
  u16* dst = A + (b * 4096 + h) * 256 + c0;
#pragma unroll 4
  for (int i = 0; i < 16; ++i) {
    int w = q * 16 + i;
    dst[w * 16384 + lane] = lT[lane][w];
  }
}

// ------- q_avg[b][o] = softmax_o( Wl[o,:] . mean_c ) -------
__global__ __launch_bounds__(256) void k_qavg(const float* __restrict__ meansum,
                                              const float* __restrict__ Wl,
                                              float* __restrict__ qavg) {
  int b = blockIdx.x, t = threadIdx.x;
  __shared__ float mean[256];
  __shared__ float red[256];
  mean[t] = meansum[b * 256 + t] * (1.0f / 4096.0f);
  __syncthreads();
  const float* wr = Wl + t * 256;
  float acc = 0.0f;
  for (int c = 0; c < 256; ++c) acc = fmaf(wr[c], mean[c], acc);
  red[t] = acc; __syncthreads();
  for (int s = 128; s; s >>= 1) { if (t < s) red[t] = fmaxf(red[t], red[t + s]); __syncthreads(); }
  float mx = red[0]; __syncthreads();
  float e = __expf(acc - mx);
  red[t] = e; __syncthreads();
  for (int s = 128; s; s >>= 1) { if (t < s) red[t] += red[t + s]; __syncthreads(); }
  qavg[b * 256 + t] = e / red[0];
}

// ------- 128x128-tile bf16 MFMA GEMM (only used for Wr now, with Zsum epilogue) -------
__global__ __launch_bounds__(256, 4) void k_gemm2(const u16* __restrict__ A,
                                                  const u16* __restrict__ W,
                                                  u16* __restrict__ out, int nstride, int NT,
                                                  float* __restrict__ Zsum) {
  int nwg = gridDim.x;
  int q = nwg >> 3;
  int bid = blockIdx.x;
  int swz = (bid & 7) * q + (bid >> 3);
  int mt = swz / NT, nt = swz % NT;
  int mb = mt << 7, nb = nt << 7;
  int t = threadIdx.x, lane = t & 63, wid = t >> 6;
  int laneg = lane & 15, lk = lane >> 4;
  __shared__ __align__(16) u16 lA[128][64];
  __shared__ __align__(16) u16 lW[128][64];
  f4v acc[4][4] = {};
  int wm = wid >> 1, wn = wid & 1;
  for (int kb = 0; kb < 4; ++kb) {
    if (kb) __syncthreads();
#pragma unroll
    for (int k = 0; k < 4; ++k) {
      int rb = (wid << 5) + (k << 3);
      int r = rb + (lane >> 3);
      int cs = (lane & 7) ^ (r & 7);
      const u16* ga = A + (mb + r) * 256 + (kb << 6) + (cs << 3);
      const u16* gw = W + (nb + r) * 256 + (kb << 6) + (cs << 3);
      gl_lds16(ga, &lA[rb][0]);
      gl_lds16(gw, &lW[rb][0]);
    }
    __syncthreads();
#pragma unroll
    for (int kk = 0; kk < 2; ++kk) {
      s8v af[4], bf[4];
#pragma unroll
      for (int m = 0; m < 4; ++m) {
        int r = (wm << 6) + (m << 4) + laneg;
        int c = ((kk << 2) + lk) ^ (r & 7);
        af[m] = *(const s8v*)&lA[r][c << 3];
      }
#pragma unroll
      for (int n = 0; n < 4; ++n) {
        int r = (wn << 6) + (n << 4) + laneg;
        int c = ((kk << 2) + lk) ^ (r & 7);
        bf[n] = *(const s8v*)&lW[r][c << 3];
      }
#pragma unroll
      for (int m = 0; m < 4; ++m)
#pragma unroll
        for (int n = 0; n < 4; ++n)
          acc[m][n] = __builtin_amdgcn_mfma_f32_16x16x32_bf16(af[m], bf[n], acc[m][n], 0, 0, 0);
    }
  }
#pragma unroll
  for (int n = 0; n < 4; ++n) {
    int col = nb + (wn << 6) + (n << 4) + laneg;
    float csum = 0.f;
#pragma unroll
    for (int m = 0; m < 4; ++m) {
      int row0 = mb + (wm << 6) + (m << 4) + (lk << 2);
#pragma unroll
      for (int j = 0; j < 4; ++j) {
        float e = ex2(acc[m][n][j]);
        csum += e;
        out[(row0 + j) * nstride + col] = f2b(e);
      }
    }
    csum += __shfl_xor(csum, 16);
    csum += __shfl_xor(csum, 32);
    if (lk == 0) atomicAdd(&Zsum[((mb >> 12) << 8) + col], csum);
  }
}

// ------- FUSED bidirectional LSTM v3: x A-frags loaded DIRECTLY from global (L1-shared),
//         no x LDS staging; LDS holds only the h double-buffer. -------
// X: bf16 [s*64+t][256]; Wih: [2][512][256] scaled; Whh: [2][512][128] scaled;
// outb row = (s/64)*4096 + t*64 + s%64, cols [dir*128, dir*128+128).
__global__ __launch_bounds__(512) void k_recur_f(const u16* __restrict__ X,
                                                 const u16* __restrict__ Wih,
                                                 const u16* __restrict__ Whh,
                                                 const float* __restrict__ bias_f,
                                                 const float* __restrict__ bias_b,
                                                 u16* __restrict__ outb) {
  int dir = blockIdx.y;
  int s0 = blockIdx.x << 4;                 // 16 sequences per block
  int t = threadIdx.x, lane = t & 63, w = t >> 6;  // 8 waves
  int laneg = lane & 15, lk = lane >> 4;
  const u16* Wd = Whh + dir * 65536;
  const u16* Wi = Wih + dir * 131072;
  const float* bia = dir ? bias_b : bias_f;
  int hc = w << 4;
  // Whh B-fragments (K=128)
  s8v bfr[4][4];
#pragma unroll
  for (int g = 0; g < 4; ++g)
#pragma unroll
    for (int kk = 0; kk < 4; ++kk)
      bfr[g][kk] = *(const s8v*)(Wd + (g * 128 + hc + laneg) * 128 + kk * 32 + lk * 8);
  // Wih B-fragments (K=256)
  s8v ifr[4][8];
#pragma unroll
  for (int g = 0; g < 4; ++g)
#pragma unroll
    for (int kk = 0; kk < 8; ++kk)
      ifr[g][kk] = *(const s8v*)(Wi + (g * 128 + hc + laneg) * 256 + kk * 32 + lk * 8);
  float bval[4];
#pragma unroll
  for (int g = 0; g < 4; ++g)
    bval[g] = bia[g * 128 + hc + laneg] * ((g == 2) ? GS_G : GS_IFO);

  __shared__ __align__(16) u16 hb[2][16][136];
  for (int i = t; i < 2 * 16 * 136; i += 512) ((u16*)hb)[i] = 0;

  float cs[4] = {0.f, 0.f, 0.f, 0.f};
  int tc0 = dir ? 63 : 0;
  int dstep = dir ? -1 : 1;
  // x A-frag global base: row = seq (laneg), k-sub = lk*8 within each 32-wide chunk
  const u16* xgl = X + (s0 + laneg) * 16384 + lk * 8;
  // h-store lane mapping (coalesced rows)
  int srow = (w << 1) + (lane >> 5);        // 0..15
  int schunk = lane & 31;                   // 0..31 (8B chunks)
  int rowb = ((s0 >> 6) << 12) + (s0 & 63);
  u16* obase = outb + (dir << 7);
  __syncthreads();
  int cur = 0;
  for (int st = 0; st < 64; ++st) {
    int tc = tc0 + st * dstep;
    // 1. issue x A-frag loads for this step (16 segments x 64B; L1 serves cross-wave reuse)
    s8v xf[8];
    {
      const u16* xp = xgl + tc * 256;
#pragma unroll
      for (int kk = 0; kk < 8; ++kk)
        xf[kk] = *(const s8v*)(xp + kk * 32);
    }
    // 2. store h of previous step (reads hb[cur]; this step's writes go to hb[cur^1])
    if (st) {
      int pr = tc - dstep;
      uint2 hv = *(const uint2*)&hb[cur][srow][schunk << 2];
      *(uint2*)(obase + (rowb + pr * 64 + srow) * 256 + (schunk << 2)) = hv;
    }
    // 3. acc = bias + Whh.h first (covers x-load latency), then + Wih.x
    f4v acc[4];
#pragma unroll
    for (int g = 0; g < 4; ++g)
      acc[g] = (f4v){bval[g], bval[g], bval[g], bval[g]};
    {
      s8v afr[4];
#pragma unroll
      for (int kk = 0; kk < 4; ++kk)
        afr[kk] = *(const s8v*)&hb[cur][laneg][kk * 32 + lk * 8];
#pragma unroll
      for (int g = 0; g < 4; ++g)
#pragma unroll
        for (int kk = 0; kk < 4; ++kk)
          acc[g] = __builtin_amdgcn_mfma_f32_16x16x32_bf16(afr[kk], bfr[g][kk], acc[g], 0, 0, 0);
    }
#pragma unroll
    for (int g = 0; g < 4; ++g)
#pragma unroll
      for (int kk = 0; kk < 8; ++kk)
        acc[g] = __builtin_amdgcn_mfma_f32_16x16x32_bf16(xf[kk], ifr[g][kk], acc[g], 0, 0, 0);
    // 4. gates
    int nxt = cur ^ 1;
#pragma unroll
    for (int j = 0; j < 4; ++j) {
      float iv = rcpf(1.0f + ex2(-acc[0][j]));
      float fv = rcpf(1.0f + ex2(-acc[1][j]));
      float gv = 1.0f - 2.0f * rcpf(1.0f + ex2(acc[2][j]));
      float ov = rcpf(1.0f + ex2(-acc[3][j]));
      float c = fv * cs[j] + iv * gv;
      cs[j] = c;
      float th = 1.0f - 2.0f * rcpf(1.0f + ex2(c * GS_G));
      hb[nxt][lk * 4 + j][hc + laneg] = f2b(ov * th);
    }
    // 5. LDS-only barrier (h-store write-acks stay in flight)
    asm volatile("s_waitcnt lgkmcnt(0)" ::: "memory");
    __builtin_amdgcn_s_barrier();
    cur = nxt;
  }
  // final h store
  {
    int pr = tc0 + 63 * dstep;
    uint2 hv = *(const uint2*)&hb[cur][srow][schunk << 2];
    *(uint2*)(obase + (rowb + pr * 64 + srow) * 256 + (schunk << 2)) = hv;
  }
}

// ------- fused attention + final: att = (qavg/Z) . evf ; out = in*(1+al*sig(att)) -------
__global__ __launch_bounds__(256) void k_attfin(const u16* __restrict__ VF,
                                                const float* __restrict__ qavg,
                                                const float* __restrict__ Z,
                                                const float* __restrict__ in,
                                                const float* __restrict__ alpha,
                                                float* __restrict__ out) {
  int bx = blockIdx.x;
  int b = bx >> 6;
  int sp0 = (bx & 63) << 6;
  int t = threadIdx.x, lane = t & 63, wid = t >> 6;
  __shared__ __align__(16) float lwo[256];
  __shared__ float fac[64];
  lwo[t] = qavg[b * 256 + t] / Z[b * 256 + t];
  __syncthreads();
  float4 wo = *(const float4*)&lwo[lane * 4];
  int rowbase = b * 4096 + sp0;
#pragma unroll 4
  for (int i = 0; i < 16; ++i) {
    int r = wid * 16 + i;
    uint2 v = *(const uint2*)&VF[(rowbase + r) * 256 + lane * 4];
    float x0 = b2f((u16)(v.x & 0xffff)), x1 = b2f((u16)(v.x >> 16));
    float x2 = b2f((u16)(v.y & 0xffff)), x3 = b2f((u16)(v.y >> 16));
    float p = wo.x * x0 + wo.y * x1 + wo.z * x2 + wo.w * x3;
#pragma unroll
    for (int off = 32; off; off >>= 1) p += __shfl_xor(p, off);
    if (lane == 0) fac[r] = p;
  }
  __syncthreads();
  float al = alpha[0];
  if (t < 64) fac[t] = 1.0f + al * sigf(fac[t]);
  __syncthreads();
  int sp = t & 63;
  float f = fac[sp];
  const float* ip = in + (long)b * 1048576 + sp0 + sp;
  float* op = out + (long)b * 1048576 + sp0 + sp;
  int c0 = t >> 6;
#pragma unroll 8
  for (int c = c0; c < 256; c += 4) {
    op[c * 4096] = ip[c * 4096] * f;
  }
}

extern "C" void kernel_launch(void* const* d_in, const int* in_sizes, int n_in,
                              void* d_out, int out_size, void* d_ws, size_t ws_size,
                              hipStream_t stream) {
  const float* input   = (const float*)d_in[0];
  const float* h_Wih_f = (const float*)d_in[1];
  const float* h_Whh_f = (const float*)d_in[2];
  const float* h_b_f   = (const float*)d_in[3];
  const float* h_Wih_b = (const float*)d_in[4];
  const float* h_Whh_b = (const float*)d_in[5];
  const float* h_b_b   = (const float*)d_in[6];
  const float* v_Wih_f = (const float*)d_in[7];
  const float* v_Whh_f = (const float*)d_in[8];
  const float* v_b_f   = (const float*)d_in[9];
  const float* v_Wih_b = (const float*)d_in[10];
  const float* v_Whh_b = (const float*)d_in[11];
  const float* v_b_b   = (const float*)d_in[12];
  const float* Wr      = (const float*)d_in[13];
  const float* Wl      = (const float*)d_in[14];
  const float* alphap  = (const float*)d_in[15];

  char* ws = (char*)d_ws;
  u16* Ah     = (u16*)(ws + 0);            // 33,554,432 B  (x for horizontal; later Ar)
  u16* VF     = (u16*)(ws + 33554432);     // 33,554,432 B
  u16* Wh     = (u16*)(ws + 167772160);    // [2][512][256] bf16
  u16* Wv     = (u16*)(ws + 168296448);    // [2][512][256]
  u16* WhhH   = (u16*)(ws + 168820736);    // [2][512][128]
  u16* WhhV   = (u16*)(ws + 169082880);
  u16* Wrb    = (u16*)(ws + 169345024);    // [256][256]
  float* meansum = (float*)(ws + 169476096);
  float* qavg = (float*)(ws + 169492480);
  float* pZ   = (float*)(ws + 169541632);  // 16 KB softmax denominators
  u16* Av = (u16*)d_out;                   // horizontal biLSTM output (33.5 MB < 64 MB)
  u16* Ar = Ah;

  (void)hipMemsetAsync(meansum, 0, 16 * 256 * 4, stream);
  (void)hipMemsetAsync(pZ, 0, 16 * 256 * 4, stream);

  CvtArgs ca;
  ca.src[0] = h_Wih_f; ca.dst[0] = Wh;          ca.n4[0] = 32768; ca.scl[0] = 1; ca.sh[0] = 6;
  ca.src[1] = h_Wih_b; ca.dst[1] = Wh + 131072; ca.n4[1] = 32768; ca.scl[1] = 1; ca.sh[1] = 6;
  ca.src[2] = v_Wih_f; ca.dst[2] = Wv;          ca.n4[2] = 32768; ca.scl[2] = 1; ca.sh[2] = 6;
  ca.src[3] = v_Wih_b; ca.dst[3] = Wv + 131072; ca.n4[3] = 32768; ca.scl[3] = 1; ca.sh[3] = 6;
  ca.src[4] = h_Whh_f; ca.dst[4] = WhhH;         ca.n4[4] = 16384; ca.scl[4] = 1; ca.sh[4] = 5;
  ca.src[5] = h_Whh_b; ca.dst[5] = WhhH + 65536; ca.n4[5] = 16384; ca.scl[5] = 1; ca.sh[5] = 5;
  ca.src[6] = v_Whh_f; ca.dst[6] = WhhV;         ca.n4[6] = 16384; ca.scl[6] = 1; ca.sh[6] = 5;
  ca.src[7] = v_Whh_b; ca.dst[7] = WhhV + 65536; ca.n4[7] = 16384; ca.scl[7] = 1; ca.sh[7] = 5;
  ca.src[8] = Wr;      ca.dst[8] = Wrb;          ca.n4[8] = 16384; ca.scl[8] = 2; ca.sh[8] = 6;
  k_cvt<<<dim3(128, 9), 256, 0, stream>>>(ca);

  k_tin<<<dim3(4, 64, 16), 256, 0, stream>>>(input, Ah, meansum);
  k_qavg<<<16, 256, 0, stream>>>(meansum, Wl, qavg);

  k_recur_f<<<dim3(64, 2), 512, 0, stream>>>(Ah, Wh, WhhH, h_b_f, h_b_b, Av);
  k_recur_f<<<dim3(64, 2), 512, 0, stream>>>(Av, Wv, WhhV, v_b_f, v_b_b, Ar);
  k_gemm2<<<1024, 256, 0, stream>>>(Ar, Wrb, VF, 256, 2, pZ);

  k_attfin<<<1024, 256, 0, stream>>>(VF, qavg, pZ, input, alphap, (float*)d_out);
}